// Round 17
// baseline (473.689 us; speedup 1.0000x reference)
//
#include <hip/hip_runtime.h>
#include <hip/hip_bf16.h>

typedef _Float16 f16x4 __attribute__((ext_vector_type(4)));
typedef _Float16 f16x8 __attribute__((ext_vector_type(8)));
typedef __fp16   h16x2 __attribute__((ext_vector_type(2)));
typedef __fp16   h16x4 __attribute__((ext_vector_type(4)));
typedef float f32x16 __attribute__((ext_vector_type(16)));

#define SCALE_Q 0.17677669529663687f
#define LOG2E   1.44269504088896340f

static __device__ __forceinline__ f16x4 pack4(float a, float b, float c, float d) {
    h16x2 lo = __builtin_amdgcn_cvt_pkrtz(a, b);
    h16x2 hi = __builtin_amdgcn_cvt_pkrtz(c, d);
    h16x4 v = __builtin_shufflevector(lo, hi, 0, 1, 2, 3);
    return __builtin_bit_cast(f16x4, v);
}

static __device__ __forceinline__ float gelu_fast(float v) {
    float z = v * (1.f + 0.044715f * v * v) * 2.3026082f;
    return v * __builtin_amdgcn_rcpf(1.f + __builtin_amdgcn_exp2f(-z));
}

// ---------- ws layout (bytes) ----------
#define WQKVP_OFF  0ull        // f16 [9][6][64][8]   = 55296 B (x16 packing)
#define WPP_OFF    55296ull    // f16 [3][12][64][4]  = 18432 B (x8 packing)
#define W1P_OFF    73728ull    // f16 [12][6][64][8]  = 73728 B (x16)
#define W2P_OFF    147456ull   // f16 [3][24][64][8]  = 73728 B (x16)
#define BMT_OFF    221184ull   // f16 [8 cls][3 h][98 i][100 j] = 470400 B (*LOG2E, pad j=98,99 = -3e4)

// ---------------- prep: pack B-fragments + combined bias+mask class table ----------------
__global__ __launch_bounds__(256) void k_prep(
    const float* __restrict__ w_qkv, const float* __restrict__ w_proj,
    const float* __restrict__ w_fc1, const float* __restrict__ w_fc2,
    const float* __restrict__ btab, const int* __restrict__ relidx,
    char* __restrict__ ws) {
    _Float16* wqkvp = (_Float16*)(ws + WQKVP_OFF);
    _Float16* wpp   = (_Float16*)(ws + WPP_OFF);
    _Float16* w1p   = (_Float16*)(ws + W1P_OFF);
    _Float16* w2p   = (_Float16*)(ws + W2P_OFF);
    _Float16* bmt   = (_Float16*)(ws + BMT_OFF);
    int e = blockIdx.x * 256 + threadIdx.x;
    if (e < 27648) {                       // wqkvp16: 9 ct x 6 c x 64 l x 8 j
        int ct = e / 3072; int r = e % 3072;
        int c = r >> 9; int l = (r >> 3) & 63; int j = r & 7;
        int k = 16 * c + 8 * (l >> 5) + j, col = ct * 32 + (l & 31);
        wqkvp[e] = (_Float16)w_qkv[k * 288 + col];
    } else if (e < 36864) {                // wpp (x8): 3 ct x 12 S x 64 x 4
        int r0 = e - 27648;
        int ct = r0 / 3072; int r = r0 % 3072;
        int S = r >> 8; int li = (r >> 2) & 63; int j4 = r & 3;
        int k = 8 * S + 4 * (li >> 5) + j4, col = ct * 32 + (li & 31);
        wpp[r0] = (_Float16)w_proj[k * 96 + col];
    } else if (e < 73728) {                // w1p16: 12 nt x 6 c x 64 x 8
        int r0 = e - 36864;
        int nt = r0 / 3072; int r = r0 % 3072;
        int c = r >> 9; int l = (r >> 3) & 63; int j = r & 7;
        int k = 16 * c + 8 * (l >> 5) + j, col = nt * 32 + (l & 31);
        w1p[r0] = (_Float16)w_fc1[k * 384 + col];
    } else if (e < 110592) {               // w2p16: 3 ct x 24 c x 64 x 8
        int r0 = e - 73728;
        int ct = r0 / 12288; int r = r0 % 12288;
        int c = r >> 9; int l = (r >> 3) & 63; int j = r & 7;
        int k = 16 * c + 8 * (l >> 5) + j, col = ct * 32 + (l & 31);
        w2p[r0] = (_Float16)w_fc2[k * 96 + col];
    } else if (e < 110592 + 235200) {      // bmt[cls][h][i][100j]
        int r = e - 110592;
        int cls = r / 29400;
        int r2 = r % 29400;
        int hh = r2 / 9800;
        int ij = r2 % 9800;
        int i = ij / 100, j = ij % 100;
        if (j < 98) {
            int lab[2];
            #pragma unroll
            for (int q = 0; q < 2; ++q) {
                int t = q ? j : i;
                int td = t / 49, rr = t % 49, th = rr / 7, tw = rr % 7;
                int ld = (cls & 4) ? (td == 0 ? 1 : 2) : 0;
                int lh = (cls & 2) ? (th < 4 ? 1 : 2) : 0;
                int lw = (cls & 1) ? (tw < 4 ? 1 : 2) : 0;
                lab[q] = (ld * 3 + lh) * 3 + lw;
            }
            float mask = (lab[0] != lab[1]) ? -100.f : 0.f;
            bmt[r] = (_Float16)((btab[relidx[i * 98 + j] * 3 + hh] + mask) * LOG2E);
        } else {
            bmt[r] = (_Float16)(-30000.f);
        }
    }
}

// ---------------- fully fused block: LN1+attn+proj+residual+LN2+MLP+residual ----------------
// LDS (40,960 B):
//   phase A: xw f16[98][104] @0 (20384)
//   heads:   VTs f16[32][140] @0 | Qs f16[128][40] @20384 | Ks f16[128][40] @30624
//   proj/D:  stage f16[98][104] @0 -> xb (in-place LN2) | rowbase u32[98] @40448
//   MLP:     xb @0 | hb f16[98][96] @21632 (18816)
__global__ __launch_bounds__(256, 4) void k_fused(
    const float* __restrict__ x,
    const float* __restrict__ g1v, const float* __restrict__ b1v,
    const float* __restrict__ b_qkv, const float* __restrict__ b_proj,
    const float* __restrict__ g2v, const float* __restrict__ b2v,
    const float* __restrict__ b_fc1, const float* __restrict__ b_fc2,
    const char* __restrict__ ws,
    float* __restrict__ out) {
    __shared__ __align__(16) char smem[40960];
    _Float16* xw    = (_Float16*)smem;             // [98][104] (phase A)
    _Float16* VTs   = (_Float16*)smem;             // [32][140] (heads)
    _Float16* Qs    = (_Float16*)(smem + 20384);   // [128][40]
    _Float16* Ks    = (_Float16*)(smem + 30624);   // [128][40]
    _Float16* stage = (_Float16*)smem;             // [98][104] (proj out; becomes xb)
    _Float16* xb    = (_Float16*)smem;             // [98][104] (LN2'd, in-place)
    _Float16* hb    = (_Float16*)(smem + 21632);   // [98][96]  (FC1 quarter buffer)
    unsigned* rowbase = (unsigned*)(smem + 40448); // [98]

    const _Float16* wqkvp = (const _Float16*)(ws + WQKVP_OFF);
    const _Float16* wpp   = (const _Float16*)(ws + WPP_OFF);
    const _Float16* w1p   = (const _Float16*)(ws + W1P_OFF);
    const _Float16* w2p   = (const _Float16*)(ws + W2P_OFF);
    const _Float16* bmt   = (const _Float16*)(ws + BMT_OFF);

    const int tid = threadIdx.x;
    const int w = blockIdx.x;
    const int b = w >> 9, nwi = w & 511;
    const int dq = nwi >> 6, hq = (nwi >> 3) & 7, wq = nwi & 7;
    const int cls = ((dq == 7) << 2) | ((hq == 7) << 1) | (wq == 7);

    // ---- A: LN1 + cyclic shift gather -> xw ----
    {
        const int lane = tid & 31, sub = tid >> 5;
        for (int it = 0; it < 13; ++it) {
            int t = sub + 8 * it;
            if (t < 98) {
                int td = t / 49; int r = t - td * 49; int th = r / 7; int tw = r - th * 7;
                int gd = (dq * 2 + td + 1) & 15;
                int gh = hq * 7 + th + 3; if (gh >= 56) gh -= 56;
                int gw = wq * 7 + tw + 3; if (gw >= 56) gw -= 56;
                const float* row = x + (size_t)(((b * 16 + gd) * 56 + gh) * 56 + gw) * 96;
                float v0 = row[lane], v1 = row[lane + 32], v2 = row[lane + 64];
                float s = v0 + v1 + v2, s2 = v0 * v0 + v1 * v1 + v2 * v2;
                #pragma unroll
                for (int off = 16; off >= 1; off >>= 1) {
                    s  += __shfl_xor(s,  off, 32);
                    s2 += __shfl_xor(s2, off, 32);
                }
                float mu = s * (1.f / 96.f);
                float rs = rsqrtf(s2 * (1.f / 96.f) - mu * mu + 1e-5f);
                xw[t * 104 + lane]      = (_Float16)((v0 - mu) * rs * g1v[lane]      + b1v[lane]);
                xw[t * 104 + lane + 32] = (_Float16)((v1 - mu) * rs * g1v[lane + 32] + b1v[lane + 32]);
                xw[t * 104 + lane + 64] = (_Float16)((v2 - mu) * rs * g1v[lane + 64] + b1v[lane + 64]);
            }
        }
    }
    __syncthreads();

    const int l = tid & 63, wid = tid >> 6, n = l & 31, hi = l >> 5;
    const int mtb = wid * 32;
    const int i_q = mtb + n;               // query (token) this lane owns in S^T / O^T
    const bool iv = (i_q < 98);
    const int ir = iv ? i_q : 97;

    // ---- A-fragments loaded ONCE; xw dead afterwards ----
    f16x8 af[6];
    if (iv) {
        #pragma unroll
        for (int c = 0; c < 6; ++c)
            af[c] = *(const f16x8*)&xw[i_q * 104 + 16 * c + 8 * hi];
    } else {
        #pragma unroll
        for (int c = 0; c < 6; ++c) af[c] = f16x8{0, 0, 0, 0, 0, 0, 0, 0};
    }
    __syncthreads();

    f16x4 ofr[3][4];                       // per-head O^T B-fragments

    #pragma unroll
    for (int h = 0; h < 3; ++h) {
        // ---- QKV via 32x32x16 ----
        #pragma unroll
        for (int sel = 0; sel < 3; ++sel) {
            int ct = sel * 3 + h;
            float bias = b_qkv[sel * 96 + h * 32 + n];
            f32x16 acc;
            #pragma unroll
            for (int r2 = 0; r2 < 16; ++r2) acc[r2] = bias;
            __builtin_amdgcn_s_setprio(1);
            #pragma unroll
            for (int c = 0; c < 6; ++c) {
                f16x8 bf = *(const f16x8*)&wqkvp[((ct * 6 + c) * 64 + l) * 8];
                acc = __builtin_amdgcn_mfma_f32_32x32x16_f16(af[c], bf, acc, 0, 0, 0);
            }
            __builtin_amdgcn_s_setprio(0);
            if (sel == 2) {
                #pragma unroll
                for (int s4 = 0; s4 < 4; ++s4) {
                    f16x4 vv = pack4(acc[4 * s4 + 0], acc[4 * s4 + 1], acc[4 * s4 + 2], acc[4 * s4 + 3]);
                    int t0 = mtb + 8 * s4 + 4 * hi;
                    *(f16x4*)&VTs[n * 140 + t0] = vv;
                }
            } else {
                #pragma unroll
                for (int rg = 0; rg < 16; ++rg) {
                    int t = mtb + (rg & 3) + 8 * (rg >> 2) + 4 * hi;
                    float v = acc[rg];
                    if (sel == 0) Qs[t * 40 + n] = (_Float16)(v * (SCALE_Q * LOG2E));
                    else          Ks[t * 40 + n] = (_Float16)v;
                }
            }
        }
        __syncthreads();

        // ---- streaming S^T (C-init = bias+mask) -> exp2 -> PV ----
        {
            const _Float16* bmtp = bmt + ((size_t)(cls * 3 + h) * 98 + ir) * 100;
            f32x16 oacc;
            #pragma unroll
            for (int r2 = 0; r2 < 16; ++r2) oacc[r2] = 0.f;
            float ssum = 0.f;
            f16x8 bq[2];
            #pragma unroll
            for (int c = 0; c < 2; ++c)
                bq[c] = *(const f16x8*)&Qs[i_q * 40 + 16 * c + 8 * hi];
            __builtin_amdgcn_s_setprio(1);
            #pragma unroll
            for (int jt = 0; jt < 4; ++jt) {
                f32x16 a;
                #pragma unroll
                for (int rg4 = 0; rg4 < 4; ++rg4) {
                    int j0 = jt * 32 + 8 * rg4 + 4 * hi;
                    int j0c = (j0 < 96) ? j0 : 96;
                    f16x4 bv4 = *(const f16x4*)&bmtp[j0c];
                    bool valid = iv && (j0 < 98);
                    #pragma unroll
                    for (int q = 0; q < 4; ++q)
                        a[rg4 * 4 + q] = valid ? (float)bv4[q] : -1e30f;
                }
                #pragma unroll
                for (int c = 0; c < 2; ++c) {
                    f16x8 ak = *(const f16x8*)&Ks[(jt * 32 + n) * 40 + 16 * c + 8 * hi];
                    a = __builtin_amdgcn_mfma_f32_32x32x16_f16(ak, bq[c], a, 0, 0, 0);
                }
                #pragma unroll
                for (int rg = 0; rg < 16; ++rg) {
                    float p = __builtin_amdgcn_exp2f(a[rg]);
                    a[rg] = p;
                    ssum += p;
                }
                #pragma unroll
                for (int s4 = 0; s4 < 4; ++s4) {
                    f16x4 pf = pack4(a[4 * s4 + 0], a[4 * s4 + 1], a[4 * s4 + 2], a[4 * s4 + 3]);
                    f16x4 av = *(const f16x4*)&VTs[n * 140 + 8 * (jt * 4 + s4) + 4 * hi];
                    oacc = __builtin_amdgcn_mfma_f32_32x32x8f16(av, pf, oacc, 0, 0, 0);
                }
            }
            __builtin_amdgcn_s_setprio(0);
            ssum += __shfl_xor(ssum, 32);
            float inv = 1.f / ssum;
            #pragma unroll
            for (int s4 = 0; s4 < 4; ++s4) {
                ofr[h][s4] = pack4(oacc[4 * s4 + 0] * inv, oacc[4 * s4 + 1] * inv,
                                   oacc[4 * s4 + 2] * inv, oacc[4 * s4 + 3] * inv);
            }
        }
        __syncthreads();
    }

    // ---- C: proj -> stage f16[98][104] (packed writes) ----
    #pragma unroll
    for (int ct = 0; ct < 3; ++ct) {
        f32x16 acc;
        #pragma unroll
        for (int r2 = 0; r2 < 16; ++r2) acc[r2] = 0.f;
        __builtin_amdgcn_s_setprio(1);
        #pragma unroll
        for (int S = 0; S < 12; ++S) {
            f16x4 aw = *(const f16x4*)&wpp[((ct * 12 + S) * 64 + l) * 4];
            acc = __builtin_amdgcn_mfma_f32_32x32x8f16(aw, ofr[S >> 2][S & 3], acc, 0, 0, 0);
        }
        __builtin_amdgcn_s_setprio(0);
        if (iv) {
            #pragma unroll
            for (int s4 = 0; s4 < 4; ++s4) {
                f16x4 sv = pack4(acc[4 * s4 + 0], acc[4 * s4 + 1], acc[4 * s4 + 2], acc[4 * s4 + 3]);
                int col0 = ct * 32 + 8 * s4 + 4 * hi;
                *(f16x4*)&stage[i_q * 104 + col0] = sv;
            }
        }
    }
    __syncthreads();

    // ---- D: residual-1 write + LN2 (stage -> xb in place) + rowbase ----
    {
        const int lane = tid & 31, sub = tid >> 5;
        for (int it = 0; it < 13; ++it) {
            int t = sub + 8 * it;
            if (t < 98) {
                int td = t / 49; int r = t - td * 49; int th = r / 7; int tw = r - th * 7;
                int gd = (dq * 2 + td + 1) & 15;
                int gh = hq * 7 + th + 3; if (gh >= 56) gh -= 56;
                int gw = wq * 7 + tw + 3; if (gw >= 56) gw -= 56;
                unsigned base = (unsigned)((((b * 16 + gd) * 56 + gh) * 56 + gw) * 96);
                if (lane == 0) rowbase[t] = base;
                float v0 = x[base + lane]      + b_proj[lane]      + (float)stage[t * 104 + lane];
                float v1 = x[base + lane + 32] + b_proj[lane + 32] + (float)stage[t * 104 + lane + 32];
                float v2 = x[base + lane + 64] + b_proj[lane + 64] + (float)stage[t * 104 + lane + 64];
                out[base + lane]      = v0;
                out[base + lane + 32] = v1;
                out[base + lane + 64] = v2;
                float s = v0 + v1 + v2, s2 = v0 * v0 + v1 * v1 + v2 * v2;
                #pragma unroll
                for (int off = 16; off >= 1; off >>= 1) {
                    s  += __shfl_xor(s,  off, 32);
                    s2 += __shfl_xor(s2, off, 32);
                }
                float mu = s * (1.f / 96.f);
                float rs = rsqrtf(s2 * (1.f / 96.f) - mu * mu + 1e-5f);
                xb[t * 104 + lane]      = (_Float16)((v0 - mu) * rs * g2v[lane]      + b2v[lane]);
                xb[t * 104 + lane + 32] = (_Float16)((v1 - mu) * rs * g2v[lane + 32] + b2v[lane + 32]);
                xb[t * 104 + lane + 64] = (_Float16)((v2 - mu) * rs * g2v[lane + 64] + b2v[lane + 64]);
            }
        }
    }
    __syncthreads();

    // ---- E/F: MLP in 4 column-quarters (wave-private rows: mt = wid) ----
    const int rowA = mtb + n;
    const int rowc = (rowA < 98) ? rowA : 97;
    f16x8 axb[6];
    #pragma unroll
    for (int c = 0; c < 6; ++c)
        axb[c] = *(const f16x8*)&xb[rowc * 104 + 16 * c + 8 * hi];
    f32x16 macc0, macc1, macc2;
    #pragma unroll
    for (int r2 = 0; r2 < 16; ++r2) { macc0[r2] = 0.f; macc1[r2] = 0.f; macc2[r2] = 0.f; }

    #pragma unroll
    for (int qq = 0; qq < 4; ++qq) {
        // FC1 quarter: nt = 3qq .. 3qq+2 -> hb[98][96] (own wave's rows only)
        #pragma unroll
        for (int s = 0; s < 3; ++s) {
            int nt = qq * 3 + s;
            float bias = b_fc1[nt * 32 + n];
            f32x16 acc;
            #pragma unroll
            for (int r2 = 0; r2 < 16; ++r2) acc[r2] = bias;
            __builtin_amdgcn_s_setprio(1);
            #pragma unroll
            for (int c = 0; c < 6; ++c) {
                f16x8 bf = *(const f16x8*)&w1p[((nt * 6 + c) * 64 + l) * 8];
                acc = __builtin_amdgcn_mfma_f32_32x32x16_f16(axb[c], bf, acc, 0, 0, 0);
            }
            __builtin_amdgcn_s_setprio(0);
            #pragma unroll
            for (int rg = 0; rg < 16; ++rg) {
                int t = mtb + (rg & 3) + 8 * (rg >> 2) + 4 * hi;
                if (t < 98) hb[t * 96 + s * 32 + n] = (_Float16)gelu_fast(acc[rg]);
            }
        }
        // FC2 quarter: accumulate over this quarter's 96 k-values (same wave's rows)
        __builtin_amdgcn_s_setprio(1);
        #pragma unroll
        for (int c2 = 0; c2 < 6; ++c2) {
            f16x8 ah = *(const f16x8*)&hb[rowc * 96 + 16 * c2 + 8 * hi];
            f16x8 bf0 = *(const f16x8*)&w2p[((0 * 24 + qq * 6 + c2) * 64 + l) * 8];
            f16x8 bf1 = *(const f16x8*)&w2p[((1 * 24 + qq * 6 + c2) * 64 + l) * 8];
            f16x8 bf2 = *(const f16x8*)&w2p[((2 * 24 + qq * 6 + c2) * 64 + l) * 8];
            macc0 = __builtin_amdgcn_mfma_f32_32x32x16_f16(ah, bf0, macc0, 0, 0, 0);
            macc1 = __builtin_amdgcn_mfma_f32_32x32x16_f16(ah, bf1, macc1, 0, 0, 0);
            macc2 = __builtin_amdgcn_mfma_f32_32x32x16_f16(ah, bf2, macc2, 0, 0, 0);
        }
        __builtin_amdgcn_s_setprio(0);
    }

    // ---- G: residual-2 scatter (rows are wave-private; out rows written in D) ----
    {
        float bb0 = b_fc2[n], bb1 = b_fc2[32 + n], bb2 = b_fc2[64 + n];
        #pragma unroll
        for (int rg = 0; rg < 16; ++rg) {
            int t = mtb + (rg & 3) + 8 * (rg >> 2) + 4 * hi;
            if (t < 98) {
                unsigned base = rowbase[t];
                out[base + n]      += macc0[rg] + bb0;
                out[base + 32 + n] += macc1[rg] + bb1;
                out[base + 64 + n] += macc2[rg] + bb2;
            }
        }
    }
}

extern "C" void kernel_launch(void* const* d_in, const int* in_sizes, int n_in,
                              void* d_out, int out_size, void* d_ws, size_t ws_size,
                              hipStream_t stream) {
    const float* x      = (const float*)d_in[0];
    const float* g1     = (const float*)d_in[2];
    const float* b1     = (const float*)d_in[3];
    const float* w_qkv  = (const float*)d_in[4];
    const float* b_qkv  = (const float*)d_in[5];
    const float* w_proj = (const float*)d_in[6];
    const float* b_proj = (const float*)d_in[7];
    const float* btab   = (const float*)d_in[8];
    const int*   relidx = (const int*)d_in[9];
    const float* g2     = (const float*)d_in[10];
    const float* b2     = (const float*)d_in[11];
    const float* w_fc1  = (const float*)d_in[12];
    const float* b_fc1  = (const float*)d_in[13];
    const float* w_fc2  = (const float*)d_in[14];
    const float* b_fc2  = (const float*)d_in[15];
    float* out = (float*)d_out;
    char*  ws  = (char*)d_ws;

    hipLaunchKernelGGL(k_prep, dim3(1351), dim3(256), 0, stream,
                       w_qkv, w_proj, w_fc1, w_fc2, btab, relidx, ws);
    hipLaunchKernelGGL(k_fused, dim3(4096), dim3(256), 0, stream,
                       x, g1, b1, b_qkv, b_proj, g2, b2, b_fc1, b_fc2,
                       (const char*)ws, out);
}

// Round 18
// 331.964 us; speedup vs baseline: 1.4269x; 1.4269x over previous
//
#include <hip/hip_runtime.h>
#include <hip/hip_bf16.h>

typedef _Float16 f16x4 __attribute__((ext_vector_type(4)));
typedef _Float16 f16x8 __attribute__((ext_vector_type(8)));
typedef __fp16   h16x2 __attribute__((ext_vector_type(2)));
typedef __fp16   h16x4 __attribute__((ext_vector_type(4)));
typedef float f32x16 __attribute__((ext_vector_type(16)));

#define SCALE_Q 0.17677669529663687f
#define LOG2E   1.44269504088896340f

static __device__ __forceinline__ f16x4 pack4(float a, float b, float c, float d) {
    h16x2 lo = __builtin_amdgcn_cvt_pkrtz(a, b);
    h16x2 hi = __builtin_amdgcn_cvt_pkrtz(c, d);
    h16x4 v = __builtin_shufflevector(lo, hi, 0, 1, 2, 3);
    return __builtin_bit_cast(f16x4, v);
}

static __device__ __forceinline__ float gelu_fast(float v) {
    float z = v * (1.f + 0.044715f * v * v) * 2.3026082f;
    return v * __builtin_amdgcn_rcpf(1.f + __builtin_amdgcn_exp2f(-z));
}

// ---------- ws layout (bytes) ----------
#define WQKVP_OFF  0ull        // f16 [9][6][64][8]   = 55296 B (x16 packing)
#define WPP_OFF    55296ull    // f16 [3][12][64][4]  = 18432 B (x8 packing)
#define W1P_OFF    73728ull    // f16 [12][6][64][8]  = 73728 B (x16)
#define W2P_OFF    147456ull   // f16 [3][24][64][8]  = 73728 B (x16)
#define BMT_OFF    221184ull   // f16 [8 cls][3 h][98 i][100 j] = 470400 B (*LOG2E, pad j=98,99 = -3e4)

// ---------------- prep: pack B-fragments + combined bias+mask class table ----------------
__global__ __launch_bounds__(256) void k_prep(
    const float* __restrict__ w_qkv, const float* __restrict__ w_proj,
    const float* __restrict__ w_fc1, const float* __restrict__ w_fc2,
    const float* __restrict__ btab, const int* __restrict__ relidx,
    char* __restrict__ ws) {
    _Float16* wqkvp = (_Float16*)(ws + WQKVP_OFF);
    _Float16* wpp   = (_Float16*)(ws + WPP_OFF);
    _Float16* w1p   = (_Float16*)(ws + W1P_OFF);
    _Float16* w2p   = (_Float16*)(ws + W2P_OFF);
    _Float16* bmt   = (_Float16*)(ws + BMT_OFF);
    int e = blockIdx.x * 256 + threadIdx.x;
    if (e < 27648) {                       // wqkvp16: 9 ct x 6 c x 64 l x 8 j
        int ct = e / 3072; int r = e % 3072;
        int c = r >> 9; int l = (r >> 3) & 63; int j = r & 7;
        int k = 16 * c + 8 * (l >> 5) + j, col = ct * 32 + (l & 31);
        wqkvp[e] = (_Float16)w_qkv[k * 288 + col];
    } else if (e < 36864) {                // wpp (x8): 3 ct x 12 S x 64 x 4
        int r0 = e - 27648;
        int ct = r0 / 3072; int r = r0 % 3072;
        int S = r >> 8; int li = (r >> 2) & 63; int j4 = r & 3;
        int k = 8 * S + 4 * (li >> 5) + j4, col = ct * 32 + (li & 31);
        wpp[r0] = (_Float16)w_proj[k * 96 + col];
    } else if (e < 73728) {                // w1p16: 12 nt x 6 c x 64 x 8
        int r0 = e - 36864;
        int nt = r0 / 3072; int r = r0 % 3072;
        int c = r >> 9; int l = (r >> 3) & 63; int j = r & 7;
        int k = 16 * c + 8 * (l >> 5) + j, col = nt * 32 + (l & 31);
        w1p[r0] = (_Float16)w_fc1[k * 384 + col];
    } else if (e < 110592) {               // w2p16: 3 ct x 24 c x 64 x 8
        int r0 = e - 73728;
        int ct = r0 / 12288; int r = r0 % 12288;
        int c = r >> 9; int l = (r >> 3) & 63; int j = r & 7;
        int k = 16 * c + 8 * (l >> 5) + j, col = ct * 32 + (l & 31);
        w2p[r0] = (_Float16)w_fc2[k * 96 + col];
    } else if (e < 110592 + 235200) {      // bmt[cls][h][i][100j]
        int r = e - 110592;
        int cls = r / 29400;
        int r2 = r % 29400;
        int hh = r2 / 9800;
        int ij = r2 % 9800;
        int i = ij / 100, j = ij % 100;
        if (j < 98) {
            int lab[2];
            #pragma unroll
            for (int q = 0; q < 2; ++q) {
                int t = q ? j : i;
                int td = t / 49, rr = t % 49, th = rr / 7, tw = rr % 7;
                int ld = (cls & 4) ? (td == 0 ? 1 : 2) : 0;
                int lh = (cls & 2) ? (th < 4 ? 1 : 2) : 0;
                int lw = (cls & 1) ? (tw < 4 ? 1 : 2) : 0;
                lab[q] = (ld * 3 + lh) * 3 + lw;
            }
            float mask = (lab[0] != lab[1]) ? -100.f : 0.f;
            bmt[r] = (_Float16)((btab[relidx[i * 98 + j] * 3 + hh] + mask) * LOG2E);
        } else {
            bmt[r] = (_Float16)(-30000.f);
        }
    }
}

// ---------------- fused attention: one block per window, 4 blocks/CU (R16 best-known) ----------------
// LDS (40,864 B): xw f16[98][104] @0 (dead after af load; VTs f16[32][140] aliases @0;
//   stage f16[98][100] aliases @0 after heads) | Qs f16[128][40] @20384 | Ks f16[128][40] @30624
__global__ __launch_bounds__(256, 4) void k_attn15(
    const float* __restrict__ x,
    const float* __restrict__ g1v, const float* __restrict__ b1v,
    const float* __restrict__ b_qkv, const float* __restrict__ b_proj,
    const char* __restrict__ ws,
    float* __restrict__ out) {
    __shared__ __align__(16) char smem[40864];
    _Float16* xw    = (_Float16*)smem;             // [98][104] (phase 1 only)
    _Float16* VTs   = (_Float16*)smem;             // [32][140] (alias, after af load)
    _Float16* Qs    = (_Float16*)(smem + 20384);   // [128][40]
    _Float16* Ks    = (_Float16*)(smem + 30624);   // [128][40]
    _Float16* stage = (_Float16*)smem;             // [98][100] (after heads)

    const _Float16* wqkvp = (const _Float16*)(ws + WQKVP_OFF);
    const _Float16* wpp   = (const _Float16*)(ws + WPP_OFF);
    const _Float16* bmt   = (const _Float16*)(ws + BMT_OFF);

    const int tid = threadIdx.x;
    const int w = blockIdx.x;
    const int b = w >> 9, nwi = w & 511;
    const int dq = nwi >> 6, hq = (nwi >> 3) & 7, wq = nwi & 7;
    const int cls = ((dq == 7) << 2) | ((hq == 7) << 1) | (wq == 7);

    // ---- LN1 + cyclic shift gather -> xw ----
    {
        const int lane = tid & 31, sub = tid >> 5;
        for (int it = 0; it < 13; ++it) {
            int t = sub + 8 * it;
            if (t < 98) {
                int td = t / 49; int r = t - td * 49; int th = r / 7; int tw = r - th * 7;
                int gd = (dq * 2 + td + 1) & 15;
                int gh = hq * 7 + th + 3; if (gh >= 56) gh -= 56;
                int gw = wq * 7 + tw + 3; if (gw >= 56) gw -= 56;
                const float* row = x + (size_t)(((b * 16 + gd) * 56 + gh) * 56 + gw) * 96;
                float v0 = row[lane], v1 = row[lane + 32], v2 = row[lane + 64];
                float s = v0 + v1 + v2, s2 = v0 * v0 + v1 * v1 + v2 * v2;
                #pragma unroll
                for (int off = 16; off >= 1; off >>= 1) {
                    s  += __shfl_xor(s,  off, 32);
                    s2 += __shfl_xor(s2, off, 32);
                }
                float mu = s * (1.f / 96.f);
                float rs = rsqrtf(s2 * (1.f / 96.f) - mu * mu + 1e-5f);
                xw[t * 104 + lane]      = (_Float16)((v0 - mu) * rs * g1v[lane]      + b1v[lane]);
                xw[t * 104 + lane + 32] = (_Float16)((v1 - mu) * rs * g1v[lane + 32] + b1v[lane + 32]);
                xw[t * 104 + lane + 64] = (_Float16)((v2 - mu) * rs * g1v[lane + 64] + b1v[lane + 64]);
            }
        }
    }
    __syncthreads();

    const int l = tid & 63, wid = tid >> 6, n = l & 31, hi = l >> 5;
    const int mtb = wid * 32;
    const int i_q = mtb + n;               // query (token) this lane owns in S^T / O^T
    const bool iv = (i_q < 98);
    const int ir = iv ? i_q : 97;

    // ---- A-fragments loaded ONCE; xw dead afterwards (region reused as VTs/stage) ----
    f16x8 af[6];
    if (iv) {
        #pragma unroll
        for (int c = 0; c < 6; ++c)
            af[c] = *(const f16x8*)&xw[i_q * 104 + 16 * c + 8 * hi];
    } else {
        #pragma unroll
        for (int c = 0; c < 6; ++c) af[c] = f16x8{0, 0, 0, 0, 0, 0, 0, 0};
    }
    __syncthreads();   // all xw reads complete before VTs writes land in the same region

    f16x4 ofr[3][4];                       // per-head O^T B-fragments

    #pragma unroll
    for (int h = 0; h < 3; ++h) {
        // ---- QKV (D[m=t][n=hd]) via 32x32x16 ----
        #pragma unroll
        for (int sel = 0; sel < 3; ++sel) {
            int ct = sel * 3 + h;
            float bias = b_qkv[sel * 96 + h * 32 + n];
            f32x16 acc;
            #pragma unroll
            for (int r2 = 0; r2 < 16; ++r2) acc[r2] = bias;
            __builtin_amdgcn_s_setprio(1);
            #pragma unroll
            for (int c = 0; c < 6; ++c) {
                f16x8 bf = *(const f16x8*)&wqkvp[((ct * 6 + c) * 64 + l) * 8];
                acc = __builtin_amdgcn_mfma_f32_32x32x16_f16(af[c], bf, acc, 0, 0, 0);
            }
            __builtin_amdgcn_s_setprio(0);
            if (sel == 2) {
                // V: packed f16x4 writes, token-consecutive (garbage tails masked by pf=0)
                #pragma unroll
                for (int s4 = 0; s4 < 4; ++s4) {
                    f16x4 vv = pack4(acc[4 * s4 + 0], acc[4 * s4 + 1], acc[4 * s4 + 2], acc[4 * s4 + 3]);
                    int t0 = mtb + 8 * s4 + 4 * hi;
                    *(f16x4*)&VTs[n * 140 + t0] = vv;
                }
            } else {
                #pragma unroll
                for (int rg = 0; rg < 16; ++rg) {
                    int t = mtb + (rg & 3) + 8 * (rg >> 2) + 4 * hi;
                    float v = acc[rg];
                    if (sel == 0) Qs[t * 40 + n] = (_Float16)(v * (SCALE_Q * LOG2E));
                    else          Ks[t * 40 + n] = (_Float16)v;
                }
            }
        }
        __syncthreads();

        // ---- streaming S^T (C-init = bias+mask via vector loads) -> exp2 -> PV ----
        {
            const _Float16* bmtp = bmt + ((size_t)(cls * 3 + h) * 98 + ir) * 100;
            f32x16 oacc;
            #pragma unroll
            for (int r2 = 0; r2 < 16; ++r2) oacc[r2] = 0.f;
            float ssum = 0.f;
            f16x8 bq[2];
            #pragma unroll
            for (int c = 0; c < 2; ++c)
                bq[c] = *(const f16x8*)&Qs[i_q * 40 + 16 * c + 8 * hi];
            __builtin_amdgcn_s_setprio(1);
            #pragma unroll
            for (int jt = 0; jt < 4; ++jt) {
                f32x16 a;
                #pragma unroll
                for (int rg4 = 0; rg4 < 4; ++rg4) {
                    int j0 = jt * 32 + 8 * rg4 + 4 * hi;
                    int j0c = (j0 < 96) ? j0 : 96;          // clamp addr; value selected below
                    f16x4 bv4 = *(const f16x4*)&bmtp[j0c];  // pad cols 98,99 carry -3e4
                    bool valid = iv && (j0 < 98);
                    #pragma unroll
                    for (int q = 0; q < 4; ++q)
                        a[rg4 * 4 + q] = valid ? (float)bv4[q] : -1e30f;
                }
                #pragma unroll
                for (int c = 0; c < 2; ++c) {
                    f16x8 ak = *(const f16x8*)&Ks[(jt * 32 + n) * 40 + 16 * c + 8 * hi];
                    a = __builtin_amdgcn_mfma_f32_32x32x16_f16(ak, bq[c], a, 0, 0, 0);
                }
                #pragma unroll
                for (int rg = 0; rg < 16; ++rg) {
                    float p = __builtin_amdgcn_exp2f(a[rg]);
                    a[rg] = p;
                    ssum += p;
                }
                #pragma unroll
                for (int s4 = 0; s4 < 4; ++s4) {
                    f16x4 pf = pack4(a[4 * s4 + 0], a[4 * s4 + 1], a[4 * s4 + 2], a[4 * s4 + 3]);
                    f16x4 av = *(const f16x4*)&VTs[n * 140 + 8 * (jt * 4 + s4) + 4 * hi];
                    oacc = __builtin_amdgcn_mfma_f32_32x32x8f16(av, pf, oacc, 0, 0, 0);
                }
            }
            __builtin_amdgcn_s_setprio(0);
            ssum += __shfl_xor(ssum, 32);
            float inv = 1.f / ssum;
            #pragma unroll
            for (int s4 = 0; s4 < 4; ++s4) {
                ofr[h][s4] = pack4(oacc[4 * s4 + 0] * inv, oacc[4 * s4 + 1] * inv,
                                   oacc[4 * s4 + 2] * inv, oacc[4 * s4 + 3] * inv);
            }
        }
        __syncthreads();   // Qs/Ks/VTs reads done before next head's writes (and stage alias)
    }

    // ---- proj: OUT^T[col][t] ; B = O^T from registers (x8); packed f16 stage writes ----
    #pragma unroll
    for (int ct = 0; ct < 3; ++ct) {
        f32x16 acc;
        #pragma unroll
        for (int r2 = 0; r2 < 16; ++r2) acc[r2] = 0.f;
        __builtin_amdgcn_s_setprio(1);
        #pragma unroll
        for (int S = 0; S < 12; ++S) {
            f16x4 aw = *(const f16x4*)&wpp[((ct * 12 + S) * 64 + l) * 4];
            acc = __builtin_amdgcn_mfma_f32_32x32x8f16(aw, ofr[S >> 2][S & 3], acc, 0, 0, 0);
        }
        __builtin_amdgcn_s_setprio(0);
        if (iv) {
            #pragma unroll
            for (int s4 = 0; s4 < 4; ++s4) {
                f16x4 sv = pack4(acc[4 * s4 + 0], acc[4 * s4 + 1], acc[4 * s4 + 2], acc[4 * s4 + 3]);
                int col0 = ct * 32 + 8 * s4 + 4 * hi;
                *(f16x4*)&stage[i_q * 100 + col0] = sv;
            }
        }
    }
    __syncthreads();
    // ---- out = x + stage + b_proj (coalesced float4) ----
    for (int e = tid; e < 2352; e += 256) {
        int t = e / 24, q4 = (e - (e / 24) * 24) * 4;
        int td = t / 49; int r = t - td * 49; int th = r / 7; int tw = r - th * 7;
        int gd = (dq * 2 + td + 1) & 15;
        int gh = hq * 7 + th + 3; if (gh >= 56) gh -= 56;
        int gw = wq * 7 + tw + 3; if (gw >= 56) gw -= 56;
        size_t base = (size_t)(((b * 16 + gd) * 56 + gh) * 56 + gw) * 96 + q4;
        float4 xv = *(const float4*)&x[base];
        float4 bp = *(const float4*)&b_proj[q4];
        f16x4 sv = *(const f16x4*)&stage[t * 100 + q4];
        float4 ov;
        ov.x = xv.x + bp.x + (float)sv[0];
        ov.y = xv.y + bp.y + (float)sv[1];
        ov.z = xv.z + bp.z + (float)sv[2];
        ov.w = xv.w + bp.w + (float)sv[3];
        *(float4*)&out[base] = ov;
    }
}

// ---------------- MLP: LN2 + FC1 + GELU + FC2 + residual (res kept in LDS; no out re-read) ----------------
// LDS: xb f16[32][104] 6656 | hb f16[32][392] 25088 | res f16[32][96] 6144 = 37,888 B -> 4 blocks/CU
__global__ __launch_bounds__(256, 4) void k_mlp7(
    const float* __restrict__ g2v, const float* __restrict__ b2v,
    const float* __restrict__ b_fc1, const float* __restrict__ b_fc2,
    const char* __restrict__ ws,
    float* __restrict__ out) {
    __shared__ __align__(16) _Float16 xb[32 * 104];
    __shared__ __align__(16) _Float16 hb[32 * 392];
    __shared__ __align__(16) _Float16 res[32 * 96];
    const _Float16* w1p = (const _Float16*)(ws + W1P_OFF);
    const _Float16* w2p = (const _Float16*)(ws + W2P_OFF);
    const int tid = threadIdx.x;
    const size_t tokBase = (size_t)blockIdx.x * 32;
    // LN2 -> xb ; residual -> res (f16)
    {
        const int lane = tid & 31, sub = tid >> 5;
        #pragma unroll
        for (int it = 0; it < 4; ++it) {
            int rt = sub + 8 * it;
            const float* row = out + (tokBase + rt) * 96;
            float v0 = row[lane], v1 = row[lane + 32], v2 = row[lane + 64];
            res[rt * 96 + lane]      = (_Float16)v0;
            res[rt * 96 + lane + 32] = (_Float16)v1;
            res[rt * 96 + lane + 64] = (_Float16)v2;
            float s = v0 + v1 + v2, s2 = v0 * v0 + v1 * v1 + v2 * v2;
            #pragma unroll
            for (int off = 16; off >= 1; off >>= 1) {
                s  += __shfl_xor(s,  off, 32);
                s2 += __shfl_xor(s2, off, 32);
            }
            float mu = s * (1.f / 96.f);
            float rs = rsqrtf(s2 * (1.f / 96.f) - mu * mu + 1e-5f);
            xb[rt * 104 + lane]      = (_Float16)((v0 - mu) * rs * g2v[lane]      + b2v[lane]);
            xb[rt * 104 + lane + 32] = (_Float16)((v1 - mu) * rs * g2v[lane + 32] + b2v[lane + 32]);
            xb[rt * 104 + lane + 64] = (_Float16)((v2 - mu) * rs * g2v[lane + 64] + b2v[lane + 64]);
        }
    }
    __syncthreads();
    const int l = tid & 63, wid = tid >> 6, n = l & 31, hi = l >> 5;
    // FC1 + GELU -> hb  (12 nt tiles over 4 waves = 3 each)
    {
        f16x8 af[6];
        #pragma unroll
        for (int c = 0; c < 6; ++c)
            af[c] = *(const f16x8*)&xb[n * 104 + 16 * c + 8 * hi];
        #pragma unroll
        for (int s3 = 0; s3 < 3; ++s3) {
            int nt = wid + 4 * s3;
            float bias = b_fc1[nt * 32 + n];
            f32x16 acc;
            #pragma unroll
            for (int r2 = 0; r2 < 16; ++r2) acc[r2] = bias;
            __builtin_amdgcn_s_setprio(1);
            #pragma unroll
            for (int c = 0; c < 6; ++c) {
                f16x8 bf = *(const f16x8*)&w1p[((nt * 6 + c) * 64 + l) * 8];
                acc = __builtin_amdgcn_mfma_f32_32x32x16_f16(af[c], bf, acc, 0, 0, 0);
            }
            __builtin_amdgcn_s_setprio(0);
            #pragma unroll
            for (int rg = 0; rg < 16; ++rg) {
                int t = (rg & 3) + 8 * (rg >> 2) + 4 * hi;
                hb[t * 392 + nt * 32 + n] = (_Float16)gelu_fast(acc[rg]);
            }
        }
    }
    __syncthreads();
    // FC2 + residual from LDS (3 ct tiles on waves 0..2; no out re-read)
    if (wid < 3) {
        int ct = wid;
        float bias = b_fc2[ct * 32 + n];
        f32x16 acc;
        #pragma unroll
        for (int r2 = 0; r2 < 16; ++r2) acc[r2] = bias;
        __builtin_amdgcn_s_setprio(1);
        #pragma unroll
        for (int c = 0; c < 24; ++c) {
            f16x8 ah = *(const f16x8*)&hb[n * 392 + 16 * c + 8 * hi];
            f16x8 bf = *(const f16x8*)&w2p[((ct * 24 + c) * 64 + l) * 8];
            acc = __builtin_amdgcn_mfma_f32_32x32x16_f16(ah, bf, acc, 0, 0, 0);
        }
        __builtin_amdgcn_s_setprio(0);
        #pragma unroll
        for (int rg = 0; rg < 16; ++rg) {
            int t = (rg & 3) + 8 * (rg >> 2) + 4 * hi;
            size_t idx = (tokBase + t) * 96 + ct * 32 + n;
            out[idx] = (float)res[t * 96 + ct * 32 + n] + acc[rg];
        }
    }
}

extern "C" void kernel_launch(void* const* d_in, const int* in_sizes, int n_in,
                              void* d_out, int out_size, void* d_ws, size_t ws_size,
                              hipStream_t stream) {
    const float* x      = (const float*)d_in[0];
    const float* g1     = (const float*)d_in[2];
    const float* b1     = (const float*)d_in[3];
    const float* w_qkv  = (const float*)d_in[4];
    const float* b_qkv  = (const float*)d_in[5];
    const float* w_proj = (const float*)d_in[6];
    const float* b_proj = (const float*)d_in[7];
    const float* btab   = (const float*)d_in[8];
    const int*   relidx = (const int*)d_in[9];
    const float* g2     = (const float*)d_in[10];
    const float* b2     = (const float*)d_in[11];
    const float* w_fc1  = (const float*)d_in[12];
    const float* b_fc1  = (const float*)d_in[13];
    const float* w_fc2  = (const float*)d_in[14];
    const float* b_fc2  = (const float*)d_in[15];
    float* out = (float*)d_out;
    char*  ws  = (char*)d_ws;

    hipLaunchKernelGGL(k_prep, dim3(1351), dim3(256), 0, stream,
                       w_qkv, w_proj, w_fc1, w_fc2, btab, relidx, ws);
    hipLaunchKernelGGL(k_attn15, dim3(4096), dim3(256), 0, stream,
                       x, g1, b1, b_qkv, b_proj, (const char*)ws, out);
    hipLaunchKernelGGL(k_mlp7, dim3(401408 / 32), dim3(256), 0, stream,
                       g2, b2, b_fc1, b_fc2, (const char*)ws, out);
}

// Round 19
// 327.532 us; speedup vs baseline: 1.4462x; 1.0135x over previous
//
#include <hip/hip_runtime.h>
#include <hip/hip_bf16.h>

typedef _Float16 f16x4 __attribute__((ext_vector_type(4)));
typedef _Float16 f16x8 __attribute__((ext_vector_type(8)));
typedef __fp16   h16x2 __attribute__((ext_vector_type(2)));
typedef __fp16   h16x4 __attribute__((ext_vector_type(4)));
typedef float f32x16 __attribute__((ext_vector_type(16)));

#define SCALE_Q 0.17677669529663687f
#define LOG2E   1.44269504088896340f

static __device__ __forceinline__ f16x4 pack4(float a, float b, float c, float d) {
    h16x2 lo = __builtin_amdgcn_cvt_pkrtz(a, b);
    h16x2 hi = __builtin_amdgcn_cvt_pkrtz(c, d);
    h16x4 v = __builtin_shufflevector(lo, hi, 0, 1, 2, 3);
    return __builtin_bit_cast(f16x4, v);
}

static __device__ __forceinline__ float gelu_fast(float v) {
    float z = v * (1.f + 0.044715f * v * v) * 2.3026082f;
    return v * __builtin_amdgcn_rcpf(1.f + __builtin_amdgcn_exp2f(-z));
}

// ---------- ws layout (bytes) ----------
#define WQKVP_OFF  0ull        // f16 [9][6][64][8]   = 55296 B (x16 packing)
#define WPP_OFF    55296ull    // f16 [3][12][64][4]  = 18432 B (x8 packing)
#define W1P_OFF    73728ull    // f16 [12][6][64][8]  = 73728 B (x16)
#define W2P_OFF    147456ull   // f16 [3][24][64][8]  = 73728 B (x16)
#define BMT_OFF    221184ull   // f16 [8 cls][3 h][98 i][100 j] = 470400 B (*LOG2E, pad j=98,99 = -3e4)

// ---------------- prep: pack B-fragments + combined bias+mask class table ----------------
__global__ __launch_bounds__(256) void k_prep(
    const float* __restrict__ w_qkv, const float* __restrict__ w_proj,
    const float* __restrict__ w_fc1, const float* __restrict__ w_fc2,
    const float* __restrict__ btab, const int* __restrict__ relidx,
    char* __restrict__ ws) {
    _Float16* wqkvp = (_Float16*)(ws + WQKVP_OFF);
    _Float16* wpp   = (_Float16*)(ws + WPP_OFF);
    _Float16* w1p   = (_Float16*)(ws + W1P_OFF);
    _Float16* w2p   = (_Float16*)(ws + W2P_OFF);
    _Float16* bmt   = (_Float16*)(ws + BMT_OFF);
    int e = blockIdx.x * 256 + threadIdx.x;
    if (e < 27648) {                       // wqkvp16: 9 ct x 6 c x 64 l x 8 j
        int ct = e / 3072; int r = e % 3072;
        int c = r >> 9; int l = (r >> 3) & 63; int j = r & 7;
        int k = 16 * c + 8 * (l >> 5) + j, col = ct * 32 + (l & 31);
        wqkvp[e] = (_Float16)w_qkv[k * 288 + col];
    } else if (e < 36864) {                // wpp (x8): 3 ct x 12 S x 64 x 4
        int r0 = e - 27648;
        int ct = r0 / 3072; int r = r0 % 3072;
        int S = r >> 8; int li = (r >> 2) & 63; int j4 = r & 3;
        int k = 8 * S + 4 * (li >> 5) + j4, col = ct * 32 + (li & 31);
        wpp[r0] = (_Float16)w_proj[k * 96 + col];
    } else if (e < 73728) {                // w1p16: 12 nt x 6 c x 64 x 8
        int r0 = e - 36864;
        int nt = r0 / 3072; int r = r0 % 3072;
        int c = r >> 9; int l = (r >> 3) & 63; int j = r & 7;
        int k = 16 * c + 8 * (l >> 5) + j, col = nt * 32 + (l & 31);
        w1p[r0] = (_Float16)w_fc1[k * 384 + col];
    } else if (e < 110592) {               // w2p16: 3 ct x 24 c x 64 x 8
        int r0 = e - 73728;
        int ct = r0 / 12288; int r = r0 % 12288;
        int c = r >> 9; int l = (r >> 3) & 63; int j = r & 7;
        int k = 16 * c + 8 * (l >> 5) + j, col = ct * 32 + (l & 31);
        w2p[r0] = (_Float16)w_fc2[k * 96 + col];
    } else if (e < 110592 + 235200) {      // bmt[cls][h][i][100j]
        int r = e - 110592;
        int cls = r / 29400;
        int r2 = r % 29400;
        int hh = r2 / 9800;
        int ij = r2 % 9800;
        int i = ij / 100, j = ij % 100;
        if (j < 98) {
            int lab[2];
            #pragma unroll
            for (int q = 0; q < 2; ++q) {
                int t = q ? j : i;
                int td = t / 49, rr = t % 49, th = rr / 7, tw = rr % 7;
                int ld = (cls & 4) ? (td == 0 ? 1 : 2) : 0;
                int lh = (cls & 2) ? (th < 4 ? 1 : 2) : 0;
                int lw = (cls & 1) ? (tw < 4 ? 1 : 2) : 0;
                lab[q] = (ld * 3 + lh) * 3 + lw;
            }
            float mask = (lab[0] != lab[1]) ? -100.f : 0.f;
            bmt[r] = (_Float16)((btab[relidx[i * 98 + j] * 3 + hh] + mask) * LOG2E);
        } else {
            bmt[r] = (_Float16)(-30000.f);
        }
    }
}

// ---------------- fused attention: one block per window, 4 blocks/CU, XCD-swizzled ----------------
// LDS (40,864 B): xw f16[98][104] @0 (dead after af load; VTs f16[32][140] aliases @0;
//   stage f16[98][100] aliases @0 after heads) | Qs f16[128][40] @20384 | Ks f16[128][40] @30624
__global__ __launch_bounds__(256, 4) void k_attn16(
    const float* __restrict__ x,
    const float* __restrict__ g1v, const float* __restrict__ b1v,
    const float* __restrict__ b_qkv, const float* __restrict__ b_proj,
    const char* __restrict__ ws,
    float* __restrict__ out) {
    __shared__ __align__(16) char smem[40864];
    _Float16* xw    = (_Float16*)smem;             // [98][104] (phase 1 only)
    _Float16* VTs   = (_Float16*)smem;             // [32][140] (alias, after af load)
    _Float16* Qs    = (_Float16*)(smem + 20384);   // [128][40]
    _Float16* Ks    = (_Float16*)(smem + 30624);   // [128][40]
    _Float16* stage = (_Float16*)smem;             // [98][100] (after heads)

    const _Float16* wqkvp = (const _Float16*)(ws + WQKVP_OFF);
    const _Float16* wpp   = (const _Float16*)(ws + WPP_OFF);
    const _Float16* bmt   = (const _Float16*)(ws + BMT_OFF);

    const int tid = threadIdx.x;
    // XCD-aware swizzle (4096 % 8 == 0 -> bijective): each XCD gets a contiguous window chunk
    const int bid = blockIdx.x;
    const int w = (bid & 7) * 512 + (bid >> 3);
    const int b = w >> 9, nwi = w & 511;
    const int dq = nwi >> 6, hq = (nwi >> 3) & 7, wq = nwi & 7;
    const int cls = ((dq == 7) << 2) | ((hq == 7) << 1) | (wq == 7);

    // ---- LN1 + cyclic shift gather -> xw ----
    {
        const int lane = tid & 31, sub = tid >> 5;
        for (int it = 0; it < 13; ++it) {
            int t = sub + 8 * it;
            if (t < 98) {
                int td = t / 49; int r = t - td * 49; int th = r / 7; int tw = r - th * 7;
                int gd = (dq * 2 + td + 1) & 15;
                int gh = hq * 7 + th + 3; if (gh >= 56) gh -= 56;
                int gw = wq * 7 + tw + 3; if (gw >= 56) gw -= 56;
                const float* row = x + (size_t)(((b * 16 + gd) * 56 + gh) * 56 + gw) * 96;
                float v0 = row[lane], v1 = row[lane + 32], v2 = row[lane + 64];
                float s = v0 + v1 + v2, s2 = v0 * v0 + v1 * v1 + v2 * v2;
                #pragma unroll
                for (int off = 16; off >= 1; off >>= 1) {
                    s  += __shfl_xor(s,  off, 32);
                    s2 += __shfl_xor(s2, off, 32);
                }
                float mu = s * (1.f / 96.f);
                float rs = rsqrtf(s2 * (1.f / 96.f) - mu * mu + 1e-5f);
                xw[t * 104 + lane]      = (_Float16)((v0 - mu) * rs * g1v[lane]      + b1v[lane]);
                xw[t * 104 + lane + 32] = (_Float16)((v1 - mu) * rs * g1v[lane + 32] + b1v[lane + 32]);
                xw[t * 104 + lane + 64] = (_Float16)((v2 - mu) * rs * g1v[lane + 64] + b1v[lane + 64]);
            }
        }
    }
    __syncthreads();

    const int l = tid & 63, wid = tid >> 6, n = l & 31, hi = l >> 5;
    const int mtb = wid * 32;
    const int i_q = mtb + n;               // query (token) this lane owns in S^T / O^T
    const bool iv = (i_q < 98);
    const int ir = iv ? i_q : 97;

    // ---- A-fragments loaded ONCE; xw dead afterwards (region reused as VTs/stage) ----
    f16x8 af[6];
    if (iv) {
        #pragma unroll
        for (int c = 0; c < 6; ++c)
            af[c] = *(const f16x8*)&xw[i_q * 104 + 16 * c + 8 * hi];
    } else {
        #pragma unroll
        for (int c = 0; c < 6; ++c) af[c] = f16x8{0, 0, 0, 0, 0, 0, 0, 0};
    }
    __syncthreads();   // all xw reads complete before VTs writes land in the same region

    f16x4 ofr[3][4];                       // per-head O^T B-fragments

    #pragma unroll
    for (int h = 0; h < 3; ++h) {
        // ---- QKV (D[m=t][n=hd]) via 32x32x16 ----
        #pragma unroll
        for (int sel = 0; sel < 3; ++sel) {
            int ct = sel * 3 + h;
            float bias = b_qkv[sel * 96 + h * 32 + n];
            f32x16 acc;
            #pragma unroll
            for (int r2 = 0; r2 < 16; ++r2) acc[r2] = bias;
            __builtin_amdgcn_s_setprio(1);
            #pragma unroll
            for (int c = 0; c < 6; ++c) {
                f16x8 bf = *(const f16x8*)&wqkvp[((ct * 6 + c) * 64 + l) * 8];
                acc = __builtin_amdgcn_mfma_f32_32x32x16_f16(af[c], bf, acc, 0, 0, 0);
            }
            __builtin_amdgcn_s_setprio(0);
            if (sel == 2) {
                // V: packed f16x4 writes, token-consecutive (garbage tails masked by pf=0)
                #pragma unroll
                for (int s4 = 0; s4 < 4; ++s4) {
                    f16x4 vv = pack4(acc[4 * s4 + 0], acc[4 * s4 + 1], acc[4 * s4 + 2], acc[4 * s4 + 3]);
                    int t0 = mtb + 8 * s4 + 4 * hi;
                    *(f16x4*)&VTs[n * 140 + t0] = vv;
                }
            } else {
                #pragma unroll
                for (int rg = 0; rg < 16; ++rg) {
                    int t = mtb + (rg & 3) + 8 * (rg >> 2) + 4 * hi;
                    float v = acc[rg];
                    if (sel == 0) Qs[t * 40 + n] = (_Float16)(v * (SCALE_Q * LOG2E));
                    else          Ks[t * 40 + n] = (_Float16)v;
                }
            }
        }
        __syncthreads();

        // ---- streaming S^T (C-init = bias+mask via vector loads) -> exp2 -> PV ----
        {
            const _Float16* bmtp = bmt + ((size_t)(cls * 3 + h) * 98 + ir) * 100;
            f32x16 oacc;
            #pragma unroll
            for (int r2 = 0; r2 < 16; ++r2) oacc[r2] = 0.f;
            float ssum = 0.f;
            f16x8 bq[2];
            #pragma unroll
            for (int c = 0; c < 2; ++c)
                bq[c] = *(const f16x8*)&Qs[i_q * 40 + 16 * c + 8 * hi];
            __builtin_amdgcn_s_setprio(1);
            #pragma unroll
            for (int jt = 0; jt < 4; ++jt) {
                f32x16 a;
                #pragma unroll
                for (int rg4 = 0; rg4 < 4; ++rg4) {
                    int j0 = jt * 32 + 8 * rg4 + 4 * hi;
                    int j0c = (j0 < 96) ? j0 : 96;          // clamp addr; value selected below
                    f16x4 bv4 = *(const f16x4*)&bmtp[j0c];  // pad cols 98,99 carry -3e4
                    bool valid = iv && (j0 < 98);
                    #pragma unroll
                    for (int q = 0; q < 4; ++q)
                        a[rg4 * 4 + q] = valid ? (float)bv4[q] : -1e30f;
                }
                #pragma unroll
                for (int c = 0; c < 2; ++c) {
                    f16x8 ak = *(const f16x8*)&Ks[(jt * 32 + n) * 40 + 16 * c + 8 * hi];
                    a = __builtin_amdgcn_mfma_f32_32x32x16_f16(ak, bq[c], a, 0, 0, 0);
                }
                #pragma unroll
                for (int rg = 0; rg < 16; ++rg) {
                    float p = __builtin_amdgcn_exp2f(a[rg]);
                    a[rg] = p;
                    ssum += p;
                }
                #pragma unroll
                for (int s4 = 0; s4 < 4; ++s4) {
                    f16x4 pf = pack4(a[4 * s4 + 0], a[4 * s4 + 1], a[4 * s4 + 2], a[4 * s4 + 3]);
                    f16x4 av = *(const f16x4*)&VTs[n * 140 + 8 * (jt * 4 + s4) + 4 * hi];
                    oacc = __builtin_amdgcn_mfma_f32_32x32x8f16(av, pf, oacc, 0, 0, 0);
                }
            }
            __builtin_amdgcn_s_setprio(0);
            ssum += __shfl_xor(ssum, 32);
            float inv = 1.f / ssum;
            #pragma unroll
            for (int s4 = 0; s4 < 4; ++s4) {
                ofr[h][s4] = pack4(oacc[4 * s4 + 0] * inv, oacc[4 * s4 + 1] * inv,
                                   oacc[4 * s4 + 2] * inv, oacc[4 * s4 + 3] * inv);
            }
        }
        __syncthreads();   // Qs/Ks/VTs reads done before next head's writes (and stage alias)
    }

    // ---- proj: OUT^T[col][t] ; B = O^T from registers (x8); packed f16 stage writes ----
    #pragma unroll
    for (int ct = 0; ct < 3; ++ct) {
        f32x16 acc;
        #pragma unroll
        for (int r2 = 0; r2 < 16; ++r2) acc[r2] = 0.f;
        __builtin_amdgcn_s_setprio(1);
        #pragma unroll
        for (int S = 0; S < 12; ++S) {
            f16x4 aw = *(const f16x4*)&wpp[((ct * 12 + S) * 64 + l) * 4];
            acc = __builtin_amdgcn_mfma_f32_32x32x8f16(aw, ofr[S >> 2][S & 3], acc, 0, 0, 0);
        }
        __builtin_amdgcn_s_setprio(0);
        if (iv) {
            #pragma unroll
            for (int s4 = 0; s4 < 4; ++s4) {
                f16x4 sv = pack4(acc[4 * s4 + 0], acc[4 * s4 + 1], acc[4 * s4 + 2], acc[4 * s4 + 3]);
                int col0 = ct * 32 + 8 * s4 + 4 * hi;
                *(f16x4*)&stage[i_q * 100 + col0] = sv;
            }
        }
    }
    __syncthreads();
    // ---- out = x + stage + b_proj (coalesced float4) ----
    for (int e = tid; e < 2352; e += 256) {
        int t = e / 24, q4 = (e - (e / 24) * 24) * 4;
        int td = t / 49; int r = t - td * 49; int th = r / 7; int tw = r - th * 7;
        int gd = (dq * 2 + td + 1) & 15;
        int gh = hq * 7 + th + 3; if (gh >= 56) gh -= 56;
        int gw = wq * 7 + tw + 3; if (gw >= 56) gw -= 56;
        size_t base = (size_t)(((b * 16 + gd) * 56 + gh) * 56 + gw) * 96 + q4;
        float4 xv = *(const float4*)&x[base];
        float4 bp = *(const float4*)&b_proj[q4];
        f16x4 sv = *(const f16x4*)&stage[t * 100 + q4];
        float4 ov;
        ov.x = xv.x + bp.x + (float)sv[0];
        ov.y = xv.y + bp.y + (float)sv[1];
        ov.z = xv.z + bp.z + (float)sv[2];
        ov.w = xv.w + bp.w + (float)sv[3];
        *(float4*)&out[base] = ov;
    }
}

// ---------------- MLP: LN2 + FC1 + GELU + FC2 + residual, 32 tokens/block, 5 blocks/CU ----------------
__global__ __launch_bounds__(256, 5) void k_mlp6(
    const float* __restrict__ g2v, const float* __restrict__ b2v,
    const float* __restrict__ b_fc1, const float* __restrict__ b_fc2,
    const char* __restrict__ ws,
    float* __restrict__ out) {
    __shared__ __align__(16) _Float16 xb[32 * 104];   // 6656 B
    __shared__ __align__(16) _Float16 hb[32 * 392];   // 25088 B
    const _Float16* w1p = (const _Float16*)(ws + W1P_OFF);
    const _Float16* w2p = (const _Float16*)(ws + W2P_OFF);
    const int tid = threadIdx.x;
    const size_t tokBase = (size_t)blockIdx.x * 32;
    // LN2 -> xb
    {
        const int lane = tid & 31, sub = tid >> 5;
        #pragma unroll
        for (int it = 0; it < 4; ++it) {
            int rt = sub + 8 * it;
            const float* row = out + (tokBase + rt) * 96;
            float v0 = row[lane], v1 = row[lane + 32], v2 = row[lane + 64];
            float s = v0 + v1 + v2, s2 = v0 * v0 + v1 * v1 + v2 * v2;
            #pragma unroll
            for (int off = 16; off >= 1; off >>= 1) {
                s  += __shfl_xor(s,  off, 32);
                s2 += __shfl_xor(s2, off, 32);
            }
            float mu = s * (1.f / 96.f);
            float rs = rsqrtf(s2 * (1.f / 96.f) - mu * mu + 1e-5f);
            xb[rt * 104 + lane]      = (_Float16)((v0 - mu) * rs * g2v[lane]      + b2v[lane]);
            xb[rt * 104 + lane + 32] = (_Float16)((v1 - mu) * rs * g2v[lane + 32] + b2v[lane + 32]);
            xb[rt * 104 + lane + 64] = (_Float16)((v2 - mu) * rs * g2v[lane + 64] + b2v[lane + 64]);
        }
    }
    __syncthreads();
    const int l = tid & 63, wid = tid >> 6, n = l & 31, hi = l >> 5;
    // FC1 + GELU -> hb  (12 nt tiles over 4 waves = 3 each)
    {
        f16x8 af[6];
        #pragma unroll
        for (int c = 0; c < 6; ++c)
            af[c] = *(const f16x8*)&xb[n * 104 + 16 * c + 8 * hi];
        #pragma unroll
        for (int s3 = 0; s3 < 3; ++s3) {
            int nt = wid + 4 * s3;
            float bias = b_fc1[nt * 32 + n];
            f32x16 acc;
            #pragma unroll
            for (int r2 = 0; r2 < 16; ++r2) acc[r2] = bias;
            __builtin_amdgcn_s_setprio(1);
            #pragma unroll
            for (int c = 0; c < 6; ++c) {
                f16x8 bf = *(const f16x8*)&w1p[((nt * 6 + c) * 64 + l) * 8];
                acc = __builtin_amdgcn_mfma_f32_32x32x16_f16(af[c], bf, acc, 0, 0, 0);
            }
            __builtin_amdgcn_s_setprio(0);
            #pragma unroll
            for (int rg = 0; rg < 16; ++rg) {
                int t = (rg & 3) + 8 * (rg >> 2) + 4 * hi;
                hb[t * 392 + nt * 32 + n] = (_Float16)gelu_fast(acc[rg]);
            }
        }
    }
    __syncthreads();
    // FC2 + residual (3 ct tiles on waves 0..2)
    if (wid < 3) {
        int ct = wid;
        float bias = b_fc2[ct * 32 + n];
        f32x16 acc;
        #pragma unroll
        for (int r2 = 0; r2 < 16; ++r2) acc[r2] = bias;
        __builtin_amdgcn_s_setprio(1);
        #pragma unroll
        for (int c = 0; c < 24; ++c) {
            f16x8 ah = *(const f16x8*)&hb[n * 392 + 16 * c + 8 * hi];
            f16x8 bf = *(const f16x8*)&w2p[((ct * 24 + c) * 64 + l) * 8];
            acc = __builtin_amdgcn_mfma_f32_32x32x16_f16(ah, bf, acc, 0, 0, 0);
        }
        __builtin_amdgcn_s_setprio(0);
        #pragma unroll
        for (int rg = 0; rg < 16; ++rg) {
            int t = (rg & 3) + 8 * (rg >> 2) + 4 * hi;
            size_t idx = (tokBase + t) * 96 + ct * 32 + n;
            out[idx] = out[idx] + acc[rg];
        }
    }
}

extern "C" void kernel_launch(void* const* d_in, const int* in_sizes, int n_in,
                              void* d_out, int out_size, void* d_ws, size_t ws_size,
                              hipStream_t stream) {
    const float* x      = (const float*)d_in[0];
    const float* g1     = (const float*)d_in[2];
    const float* b1     = (const float*)d_in[3];
    const float* w_qkv  = (const float*)d_in[4];
    const float* b_qkv  = (const float*)d_in[5];
    const float* w_proj = (const float*)d_in[6];
    const float* b_proj = (const float*)d_in[7];
    const float* btab   = (const float*)d_in[8];
    const int*   relidx = (const int*)d_in[9];
    const float* g2     = (const float*)d_in[10];
    const float* b2     = (const float*)d_in[11];
    const float* w_fc1  = (const float*)d_in[12];
    const float* b_fc1  = (const float*)d_in[13];
    const float* w_fc2  = (const float*)d_in[14];
    const float* b_fc2  = (const float*)d_in[15];
    float* out = (float*)d_out;
    char*  ws  = (char*)d_ws;

    hipLaunchKernelGGL(k_prep, dim3(1351), dim3(256), 0, stream,
                       w_qkv, w_proj, w_fc1, w_fc2, btab, relidx, ws);
    hipLaunchKernelGGL(k_attn16, dim3(4096), dim3(256), 0, stream,
                       x, g1, b1, b_qkv, b_proj, (const char*)ws, out);
    hipLaunchKernelGGL(k_mlp6, dim3(401408 / 32), dim3(256), 0, stream,
                       g2, b2, b_fc1, b_fc2, (const char*)ws, out);
}